// Round 1
// baseline (2400.038 us; speedup 1.0000x reference)
//
#include <hip/hip_runtime.h>
#include <cstdint>
#include <cstddef>

#define BB   4
#define AA   256
#define NNB  64
#define FF   128
#define NBAS 20
#define NLAY 3
#define BA   (BB*AA)        // 1024 atoms total
#define EDG  (BA*NNB)       // 65536 edges

__device__ __forceinline__ float silu_f(float x){ return x / (1.0f + __expf(-x)); }

// ---------------- init: inv_node = emb[atomic_numbers] ----------------
__global__ void k_init(const int* __restrict__ z, const float* __restrict__ emb,
                       float* __restrict__ inv_node){
  int id = blockIdx.x*256 + threadIdx.x;      // BA*FF = 131072 total
  int atom = id >> 7, o = id & 127;
  inv_node[id] = emb[z[atom]*FF + o];
}

// ---------------- geometry: rbf, cutoff, unit ----------------
__global__ void k_geom(const float* __restrict__ dist, const float* __restrict__ dvec,
                       float* __restrict__ rbf, float* __restrict__ cutw,
                       float* __restrict__ unitv){
  int e = blockIdx.x*256 + threadIdx.x;       // EDG total
  float d = dist[e];
  float x = d * 0.2f;
  float x2 = x*x, x4 = x2*x2, x6 = x4*x2, x7 = x6*x, x8 = x7*x;
  float f = 1.0f - 28.0f*x6 + 48.0f*x7 - 21.0f*x8;
  f = (x < 1.0f) ? f : 0.0f;
  cutw[e] = f;
  float inv = 1.0f/(d + 1e-8f);
  unitv[(size_t)e*3+0] = dvec[(size_t)e*3+0]*inv;
  unitv[(size_t)e*3+1] = dvec[(size_t)e*3+1]*inv;
  unitv[(size_t)e*3+2] = dvec[(size_t)e*3+2]*inv;
  const float c = 0.6283185307179586f;        // pi/5
  #pragma unroll
  for (int n=1;n<=NBAS;++n)
    rbf[(size_t)e*NBAS + n-1] = sinf((float)n*c*d)*inv;
}

// ---------------- two-pass 128->128->128 MLP core over 16 rows ----------------
__device__ __forceinline__ void mlp16(const float (*xs)[FF], float (*hs)[FF], int o,
    const float* __restrict__ W1, const float* __restrict__ b1,
    const float* __restrict__ W2, const float* __restrict__ b2, float acc[16]){
  #pragma unroll
  for (int r=0;r<16;++r) acc[r] = b1 ? b1[o] : 0.0f;
  #pragma unroll
  for (int ic=0;ic<4;++ic){
    float4 wv[8];
    #pragma unroll
    for (int j=0;j<8;++j) wv[j] = *reinterpret_cast<const float4*>(&W1[(size_t)o*FF + ic*32 + j*4]);
    #pragma unroll
    for (int r=0;r<16;++r){
      #pragma unroll
      for (int j=0;j<8;++j){
        float4 xv = *reinterpret_cast<const float4*>(&xs[r][ic*32+j*4]);
        acc[r] = fmaf(xv.x, wv[j].x, acc[r]);
        acc[r] = fmaf(xv.y, wv[j].y, acc[r]);
        acc[r] = fmaf(xv.z, wv[j].z, acc[r]);
        acc[r] = fmaf(xv.w, wv[j].w, acc[r]);
      }
    }
  }
  #pragma unroll
  for (int r=0;r<16;++r) hs[r][o] = silu_f(acc[r]);
  __syncthreads();
  #pragma unroll
  for (int r=0;r<16;++r) acc[r] = b2 ? b2[o] : 0.0f;
  #pragma unroll
  for (int ic=0;ic<4;++ic){
    float4 wv[8];
    #pragma unroll
    for (int j=0;j<8;++j) wv[j] = *reinterpret_cast<const float4*>(&W2[(size_t)o*FF + ic*32 + j*4]);
    #pragma unroll
    for (int r=0;r<16;++r){
      #pragma unroll
      for (int j=0;j<8;++j){
        float4 xv = *reinterpret_cast<const float4*>(&hs[r][ic*32+j*4]);
        acc[r] = fmaf(xv.x, wv[j].x, acc[r]);
        acc[r] = fmaf(xv.y, wv[j].y, acc[r]);
        acc[r] = fmaf(xv.z, wv[j].z, acc[r]);
        acc[r] = fmaf(xv.w, wv[j].w, acc[r]);
      }
    }
  }
}

// ---------------- node MLP: Y = W2*silu(W1*X+b1)+b2 over 1024 rows ----------------
__global__ __launch_bounds__(128) void k_mlp_node(const float* __restrict__ X,
    const float* __restrict__ W1, const float* __restrict__ b1,
    const float* __restrict__ W2, const float* __restrict__ b2,
    float* __restrict__ Y){
  __shared__ __align__(16) float xs[16][FF];
  __shared__ __align__(16) float hs[16][FF];
  const int o = threadIdx.x;
  const int row0 = blockIdx.x * 16;
  #pragma unroll
  for (int r=0;r<16;++r) xs[r][o] = X[(size_t)(row0+r)*FF + o];
  __syncthreads();
  float acc[16];
  mlp16(xs, hs, o, W1, b1, W2, b2, acc);
  #pragma unroll
  for (int r=0;r<16;++r) Y[(size_t)(row0+r)*FF + o] = acc[r];
}

// ---------------- edge message: inv_msg, eq_msg_F, eq_F accumulation ----------------
__global__ __launch_bounds__(64) void k_edge_msg(
    const float* __restrict__ rbf, const float* __restrict__ cutw,
    const float* __restrict__ unitv, const float* __restrict__ maskp,
    const int* __restrict__ nbrs, const float* __restrict__ msg_node,
    const float* __restrict__ meW, const float* __restrict__ meb,
    const float* __restrict__ eqcW,
    float* __restrict__ inv_msg, float* __restrict__ eqmsgF,
    float* __restrict__ eqF){
  __shared__ float mws[FF*21];                 // 128 x 20, padded stride 21 (odd -> conflict-free)
  const int lane = threadIdx.x;
  const int atom = blockIdx.x;
  const int bbase = (atom / AA) * AA;
  for (int idx=lane; idx<FF*NBAS; idx+=64){
    int r = idx/NBAS, c2 = idx - r*NBAS;
    mws[r*21+c2] = meW[idx];
  }
  __syncthreads();
  const float mb0 = meb[lane],            mb1 = meb[lane+64];
  const float mn0 = msg_node[(size_t)atom*FF + lane];
  const float mn1 = msg_node[(size_t)atom*FF + lane + 64];
  const float ec0 = eqcW[lane],           ec1 = eqcW[lane+64];
  float accF = 0.0f;
  for (int e=0;e<NNB;++e){
    const int eg = atom*NNB + e;
    const float* rb = rbf + (size_t)eg*NBAS;
    float me0 = mb0, me1 = mb1;
    #pragma unroll
    for (int i=0;i<NBAS;++i){
      float rv = rb[i];
      me0 = fmaf(rv, mws[lane*21+i],      me0);
      me1 = fmaf(rv, mws[(lane+64)*21+i], me1);
    }
    float ct = cutw[eg];
    me0 *= ct; me1 *= ct;
    int nb = nbrs[eg];
    const float* mf = msg_node + (size_t)(bbase + nb)*FF;
    float v0 = me0 * mn0 * mf[lane];
    float v1 = me1 * mn1 * mf[lane+64];
    inv_msg[(size_t)eg*FF + lane]      = v0;
    inv_msg[(size_t)eg*FF + lane + 64] = v1;
    float pv = fmaf(v0, ec0, v1*ec1);
    #pragma unroll
    for (int s2=32; s2>0; s2>>=1) pv += __shfl_xor(pv, s2);
    if (lane < 3){
      float sm = pv * unitv[(size_t)eg*3 + lane];
      eqmsgF[(size_t)eg*3 + lane] = sm;          // stored WITHOUT mask (mask applied per-use)
      accF = fmaf(sm, maskp[eg], accF);
    }
  }
  if (lane < 3) eqF[atom*3+lane] += accF;        // zeroed at start; single writer per atom
}

// ---------------- eqf MLP over the atom's 64 edges + eq_upd_f aggregation ----------------
__global__ __launch_bounds__(128) void k_eqf(
    const float* __restrict__ inv_msg,
    const float* __restrict__ W1, const float* __restrict__ b1,
    const float* __restrict__ W2, const float* __restrict__ b2,
    const float* __restrict__ eqmsgF, const float* __restrict__ maskp,
    float* __restrict__ eqf_out, float* __restrict__ updf){
  __shared__ __align__(16) float xs[16][FF];
  __shared__ __align__(16) float hs[16][FF];
  const int o = threadIdx.x;
  const int atom = blockIdx.x;
  float af0=0.f, af1=0.f, af2=0.f;
  for (int ch=0; ch<4; ++ch){
    const int row0 = atom*NNB + ch*16;
    #pragma unroll
    for (int r=0;r<16;++r) xs[r][o] = inv_msg[(size_t)(row0+r)*FF + o];
    __syncthreads();
    float acc[16];
    mlp16(xs, hs, o, W1, b1, W2, b2, acc);
    #pragma unroll
    for (int r=0;r<16;++r){
      int eg = row0 + r;
      float ym = acc[r]*maskp[eg];
      af0 = fmaf(ym, eqmsgF[(size_t)eg*3+0], af0);
      af1 = fmaf(ym, eqmsgF[(size_t)eg*3+1], af1);
      af2 = fmaf(ym, eqmsgF[(size_t)eg*3+2], af2);
    }
    __syncthreads();
  }
  size_t b0 = (size_t)atom*3*FF;
  updf[b0       + o] = af0;  updf[b0 +   FF + o] = af1;  updf[b0 + 2*FF + o] = af2;
  eqf_out[b0       + o] += af0;
  eqf_out[b0 +   FF + o] += af1;
  eqf_out[b0 + 2*FF + o] += af2;
}

// ---------------- eme MLP (no bias) + eq_upd_dr aggregation (reads eq_dr, no write) -----
__global__ __launch_bounds__(128) void k_eme(
    const float* __restrict__ inv_msg,
    const float* __restrict__ W1, const float* __restrict__ W2,
    const int* __restrict__ nbrs, const float* __restrict__ maskp,
    const float* __restrict__ eqdr, float* __restrict__ upddr){
  __shared__ __align__(16) float xs[16][FF];
  __shared__ __align__(16) float hs[16][FF];
  const int o = threadIdx.x;
  const int atom = blockIdx.x;
  const int bbase = (atom / AA) * AA;
  float ad0=0.f, ad1=0.f, ad2=0.f;
  for (int ch=0; ch<4; ++ch){
    const int row0 = atom*NNB + ch*16;
    #pragma unroll
    for (int r=0;r<16;++r) xs[r][o] = inv_msg[(size_t)(row0+r)*FF + o];
    __syncthreads();
    float acc[16];
    mlp16(xs, hs, o, W1, nullptr, W2, nullptr, acc);
    #pragma unroll
    for (int r=0;r<16;++r){
      int eg = row0 + r;
      int nb = nbrs[eg];
      const float* gd = eqdr + (size_t)(bbase + nb)*3*FF;
      float ym = acc[r]*maskp[eg];
      ad0 = fmaf(ym, gd[o],        ad0);
      ad1 = fmaf(ym, gd[FF+o],     ad1);
      ad2 = fmaf(ym, gd[2*FF+o],   ad2);
    }
    __syncthreads();
  }
  size_t b0 = (size_t)atom*3*FF;
  upddr[b0       + o] = ad0;
  upddr[b0 +   FF + o] = ad1;
  upddr[b0 + 2*FF + o] = ad2;
}

// ---------------- finalize: eq_dr update + inv_node update ----------------
__global__ void k_fin(const float* __restrict__ esu, const float* __restrict__ isu,
                      const float* __restrict__ updf, const float* __restrict__ upddr,
                      const float* __restrict__ eqf, float* __restrict__ eqdr,
                      float* __restrict__ inv_node){
  int id = blockIdx.x*256+threadIdx.x;          // BA*FF
  int atom = id >> 7, o = id & 127;
  float es = esu[id];
  float sum = 0.f;
  size_t b0 = (size_t)atom*3*FF + o;
  #pragma unroll
  for (int c=0;c<3;++c){
    size_t k = b0 + (size_t)c*FF;
    float nd = eqdr[k] + upddr[k] + es*updf[k];
    eqdr[k] = nd;
    sum = fmaf(eqf[k], nd, sum);
  }
  inv_node[id] = fmaf(-isu[id], sum, inv_node[id]);
}

extern "C" void kernel_launch(void* const* d_in, const int* in_sizes, int n_in,
                              void* d_out, int out_size, void* d_ws, size_t ws_size,
                              hipStream_t stream){
  const int*   z     = (const int*)  d_in[0];
  const int*   nbrs  = (const int*)  d_in[2];
  const float* maskp = (const float*)d_in[3];
  const float* dist  = (const float*)d_in[4];
  const float* dvec  = (const float*)d_in[5];
  const float* emb   = (const float*)d_in[6];
  const float* me_W  = (const float*)d_in[7];
  const float* me_b  = (const float*)d_in[8];
  const float* mn_W1 = (const float*)d_in[9];
  const float* mn_b1 = (const float*)d_in[10];
  const float* mn_W2 = (const float*)d_in[11];
  const float* mn_b2 = (const float*)d_in[12];
  const float* eqc_W = (const float*)d_in[13];
  const float* eqf_W1= (const float*)d_in[14];
  const float* eqf_b1= (const float*)d_in[15];
  const float* eqf_W2= (const float*)d_in[16];
  const float* eqf_b2= (const float*)d_in[17];
  const float* esu_W1= (const float*)d_in[18];
  const float* esu_b1= (const float*)d_in[19];
  const float* esu_W2= (const float*)d_in[20];
  const float* esu_b2= (const float*)d_in[21];
  const float* eme_W1= (const float*)d_in[22];
  const float* eme_W2= (const float*)d_in[23];
  const float* isu_W1= (const float*)d_in[24];
  const float* isu_b1= (const float*)d_in[25];
  const float* isu_W2= (const float*)d_in[26];
  const float* isu_b2= (const float*)d_in[27];

  float* out      = (float*)d_out;
  float* inv_node = out;                        // BA*FF           = 131072
  float* eqF      = out + 131072;               // BA*3            = 3072
  float* eqf      = out + 134144;               // BA*3*FF         = 393216
  float* eqdr     = out + 527360;               // BA*3*FF         = 393216

  // workspace layout (floats); total 11,337,728 floats = 45.4 MB
  float* w        = (float*)d_ws;
  float* rbf      = w;                          // EDG*NBAS = 1,310,720
  float* cutw     = w + 1310720;                // EDG      =    65,536
  float* unitv    = w + 1376256;                // EDG*3    =   196,608
  float* msg_node = w + 1572864;                // BA*FF    =   131,072
  float* esu_o    = w + 1703936;                // BA*FF
  float* isu_o    = w + 1835008;                // BA*FF
  float* inv_msg  = w + 1966080;                // EDG*FF   = 8,388,608
  float* eqmsgF   = w + 10354688;               // EDG*3    =   196,608
  float* updf     = w + 10551296;               // BA*3*FF  =   393,216
  float* upddr    = w + 10944512;               // BA*3*FF  =   393,216

  // zero the accumulated output regions (eq_F, eq_f, eq_dr)
  hipMemsetAsync(out + 131072, 0, (size_t)(3072 + 2*393216)*sizeof(float), stream);

  k_init<<<BA*FF/256, 256, 0, stream>>>(z, emb, inv_node);
  k_geom<<<EDG/256,   256, 0, stream>>>(dist, dvec, rbf, cutw, unitv);

  for (int l=0; l<NLAY; ++l){
    size_t oW = (size_t)l*FF*FF, oB = (size_t)l*FF;
    k_mlp_node<<<BA/16, 128, 0, stream>>>(inv_node, mn_W1+oW,  mn_b1+oB,  mn_W2+oW,  mn_b2+oB,  msg_node);
    k_mlp_node<<<BA/16, 128, 0, stream>>>(inv_node, esu_W1+oW, esu_b1+oB, esu_W2+oW, esu_b2+oB, esu_o);
    k_mlp_node<<<BA/16, 128, 0, stream>>>(inv_node, isu_W1+oW, isu_b1+oB, isu_W2+oW, isu_b2+oB, isu_o);
    k_edge_msg<<<BA, 64, 0, stream>>>(rbf, cutw, unitv, maskp, nbrs, msg_node,
                                      me_W + (size_t)l*FF*NBAS, me_b+oB, eqc_W+oB,
                                      inv_msg, eqmsgF, eqF);
    k_eqf<<<BA, 128, 0, stream>>>(inv_msg, eqf_W1+oW, eqf_b1+oB, eqf_W2+oW, eqf_b2+oB,
                                  eqmsgF, maskp, eqf, updf);
    k_eme<<<BA, 128, 0, stream>>>(inv_msg, eme_W1+oW, eme_W2+oW, nbrs, maskp, eqdr, upddr);
    k_fin<<<BA*FF/256, 256, 0, stream>>>(esu_o, isu_o, updf, upddr, eqf, eqdr, inv_node);
  }
}

// Round 2
// 448.388 us; speedup vs baseline: 5.3526x; 5.3526x over previous
//
#include <hip/hip_runtime.h>
#include <cstdint>
#include <cstddef>

#define BB   4
#define AA   256
#define NNB  64
#define FF   128
#define NBAS 20
#define NLAY 3
#define BA   (BB*AA)        // 1024 atoms total
#define EDG  (BA*NNB)       // 65536 edges

typedef __attribute__((ext_vector_type(8))) short bf16x8;
typedef __attribute__((ext_vector_type(4))) float f32x4;

__device__ __forceinline__ float silu_f(float x){ return x / (1.0f + __expf(-x)); }

// round-to-nearest-even f32 -> bf16 bits
__device__ __forceinline__ unsigned short f2bf(float x){
  unsigned int u = __float_as_uint(x);
  u += 0x7FFFu + ((u >> 16) & 1u);
  return (unsigned short)(u >> 16);
}

// ---------------- init: inv_node = emb[atomic_numbers] ----------------
__global__ void k_init(const int* __restrict__ z, const float* __restrict__ emb,
                       float* __restrict__ inv_node){
  int id = blockIdx.x*256 + threadIdx.x;
  int atom = id >> 7, o = id & 127;
  inv_node[id] = emb[z[atom]*FF + o];
}

// ---------------- geometry: rbf, cutoff, unit ----------------
__global__ void k_geom(const float* __restrict__ dist, const float* __restrict__ dvec,
                       float* __restrict__ rbf, float* __restrict__ cutw,
                       float* __restrict__ unitv){
  int e = blockIdx.x*256 + threadIdx.x;
  float d = dist[e];
  float x = d * 0.2f;
  float x2 = x*x, x4 = x2*x2, x6 = x4*x2, x7 = x6*x, x8 = x7*x;
  float f = 1.0f - 28.0f*x6 + 48.0f*x7 - 21.0f*x8;
  f = (x < 1.0f) ? f : 0.0f;
  cutw[e] = f;
  float inv = 1.0f/(d + 1e-8f);
  unitv[(size_t)e*3+0] = dvec[(size_t)e*3+0]*inv;
  unitv[(size_t)e*3+1] = dvec[(size_t)e*3+1]*inv;
  unitv[(size_t)e*3+2] = dvec[(size_t)e*3+2]*inv;
  const float c = 0.6283185307179586f;        // pi/5
  #pragma unroll
  for (int n=1;n<=NBAS;++n)
    rbf[(size_t)e*NBAS + n-1] = sinf((float)n*c*d)*inv;
}

// ---------------- weight conversion: 4 matrices x NLAY x 128 x 128 -> bf16 ----------------
__global__ void k_cvtw(const float* __restrict__ a, const float* __restrict__ b,
                       const float* __restrict__ c, const float* __restrict__ d,
                       unsigned short* __restrict__ out){
  int id = blockIdx.x*256 + threadIdx.x;       // 4*49152 = 196608
  int reg = id / 49152, off = id - reg*49152;
  const float* src = (reg==0)?a:(reg==1)?b:(reg==2)?c:d;
  out[id] = f2bf(src[off]);
}

// ---------------- f32 two-pass MLP core over 16 rows (node MLPs) ----------------
__device__ __forceinline__ void mlp16(const float (*xs)[FF], float (*hs)[FF], int o,
    const float* __restrict__ W1, const float* __restrict__ b1,
    const float* __restrict__ W2, const float* __restrict__ b2, float acc[16]){
  #pragma unroll
  for (int r=0;r<16;++r) acc[r] = b1[o];
  #pragma unroll
  for (int ic=0;ic<4;++ic){
    float4 wv[8];
    #pragma unroll
    for (int j=0;j<8;++j) wv[j] = *reinterpret_cast<const float4*>(&W1[(size_t)o*FF + ic*32 + j*4]);
    #pragma unroll
    for (int r=0;r<16;++r){
      #pragma unroll
      for (int j=0;j<8;++j){
        float4 xv = *reinterpret_cast<const float4*>(&xs[r][ic*32+j*4]);
        acc[r] = fmaf(xv.x, wv[j].x, acc[r]);
        acc[r] = fmaf(xv.y, wv[j].y, acc[r]);
        acc[r] = fmaf(xv.z, wv[j].z, acc[r]);
        acc[r] = fmaf(xv.w, wv[j].w, acc[r]);
      }
    }
  }
  #pragma unroll
  for (int r=0;r<16;++r) hs[r][o] = silu_f(acc[r]);
  __syncthreads();
  #pragma unroll
  for (int r=0;r<16;++r) acc[r] = b2[o];
  #pragma unroll
  for (int ic=0;ic<4;++ic){
    float4 wv[8];
    #pragma unroll
    for (int j=0;j<8;++j) wv[j] = *reinterpret_cast<const float4*>(&W2[(size_t)o*FF + ic*32 + j*4]);
    #pragma unroll
    for (int r=0;r<16;++r){
      #pragma unroll
      for (int j=0;j<8;++j){
        float4 xv = *reinterpret_cast<const float4*>(&hs[r][ic*32+j*4]);
        acc[r] = fmaf(xv.x, wv[j].x, acc[r]);
        acc[r] = fmaf(xv.y, wv[j].y, acc[r]);
        acc[r] = fmaf(xv.z, wv[j].z, acc[r]);
        acc[r] = fmaf(xv.w, wv[j].w, acc[r]);
      }
    }
  }
}

// ---------------- three node MLPs in one dispatch (blockIdx.y selects) ----------------
__global__ __launch_bounds__(128) void k_mlp_node3(const float* __restrict__ X,
    const float* W1a, const float* b1a, const float* W2a, const float* b2a, float* Ya,
    const float* W1b, const float* b1b, const float* W2b, const float* b2b, float* Yb,
    const float* W1c, const float* b1c, const float* W2c, const float* b2c, float* Yc){
  const float *W1,*b1,*W2,*b2; float* Y;
  if (blockIdx.y==0){ W1=W1a;b1=b1a;W2=W2a;b2=b2a;Y=Ya; }
  else if (blockIdx.y==1){ W1=W1b;b1=b1b;W2=W2b;b2=b2b;Y=Yb; }
  else { W1=W1c;b1=b1c;W2=W2c;b2=b2c;Y=Yc; }
  __shared__ __align__(16) float xs[16][FF];
  __shared__ __align__(16) float hs[16][FF];
  const int o = threadIdx.x;
  const int row0 = blockIdx.x * 16;
  #pragma unroll
  for (int r=0;r<16;++r) xs[r][o] = X[(size_t)(row0+r)*FF + o];
  __syncthreads();
  float acc[16];
  mlp16(xs, hs, o, W1, b1, W2, b2, acc);
  #pragma unroll
  for (int r=0;r<16;++r) Y[(size_t)(row0+r)*FF + o] = acc[r];
}

// ---------------- edge message: 4 waves x 16 edges; writes bf16 inv_msg ----------------
__global__ __launch_bounds__(256) void k_edge_msg(
    const float* __restrict__ rbf, const float* __restrict__ cutw,
    const float* __restrict__ unitv, const float* __restrict__ maskp,
    const int* __restrict__ nbrs, const float* __restrict__ msg_node,
    const float* __restrict__ meW, const float* __restrict__ meb,
    const float* __restrict__ eqcW,
    unsigned short* __restrict__ inv_msg_bf, float* __restrict__ eqmsgF,
    float* __restrict__ eqF){
  __shared__ float mws[FF*21];                 // padded stride 21 -> conflict-free
  __shared__ float redF[4][3];
  const int t = threadIdx.x, w = t >> 6, l = t & 63;
  const int atom = blockIdx.x;
  const int bbase = (atom / AA) * AA;
  for (int idx=t; idx<FF*NBAS; idx+=256){
    int r = idx/NBAS, c2 = idx - r*NBAS;
    mws[r*21+c2] = meW[idx];
  }
  __syncthreads();
  const float mb0 = meb[l],            mb1 = meb[l+64];
  const float mn0 = msg_node[(size_t)atom*FF + l];
  const float mn1 = msg_node[(size_t)atom*FF + l + 64];
  const float ec0 = eqcW[l],           ec1 = eqcW[l+64];
  float accF = 0.0f;
  for (int e = w*16; e < w*16+16; ++e){
    const int eg = atom*NNB + e;
    const float* rb = rbf + (size_t)eg*NBAS;
    float me0 = mb0, me1 = mb1;
    #pragma unroll
    for (int i=0;i<NBAS;++i){
      float rv = rb[i];
      me0 = fmaf(rv, mws[l*21+i],      me0);
      me1 = fmaf(rv, mws[(l+64)*21+i], me1);
    }
    float ct = cutw[eg];
    me0 *= ct; me1 *= ct;
    int nb = nbrs[eg];
    const float* mf = msg_node + (size_t)(bbase + nb)*FF;
    float v0 = me0 * mn0 * mf[l];
    float v1 = me1 * mn1 * mf[l+64];
    inv_msg_bf[(size_t)eg*FF + l]      = f2bf(v0);
    inv_msg_bf[(size_t)eg*FF + l + 64] = f2bf(v1);
    float pv = fmaf(v0, ec0, v1*ec1);
    #pragma unroll
    for (int s2=32; s2>0; s2>>=1) pv += __shfl_xor(pv, s2);
    if (l < 3){
      float sm = pv * unitv[(size_t)eg*3 + l];
      eqmsgF[(size_t)eg*3 + l] = sm;
      accF = fmaf(sm, maskp[eg], accF);
    }
  }
  if (l < 3) redF[w][l] = accF;
  __syncthreads();
  if (t < 3) eqF[atom*3+t] += redF[0][t]+redF[1][t]+redF[2][t]+redF[3][t];
}

// ---------------- MFMA GEMM helper: 64x128 tile, K=128, per-wave 16 rows ----------------
// A: LDS row-major [64][stride=136] bf16 (lane: row=w*16+(l&15), k=ks*32+(l>>4)*8)
// B: global row-major W [128 out][128 in] bf16 (lane: n=nt*16+(l&15), same k)
// D: col = nt*16+(l&15), row = w*16+(l>>4)*4+reg      (m89/m97-verified layouts)
__device__ __forceinline__ void gemm_tile(const unsigned short* Xs,
    const unsigned short* __restrict__ Wg, int w, int l, f32x4 acc[8]){
  bf16x8 afr[4];
  #pragma unroll
  for (int ks=0; ks<4; ++ks)
    afr[ks] = *(const bf16x8*)(Xs + (w*16 + (l&15))*136 + ks*32 + ((l>>4)<<3));
  #pragma unroll
  for (int nt=0; nt<8; ++nt){
    #pragma unroll
    for (int ks=0; ks<4; ++ks){
      bf16x8 bfr = *(const bf16x8*)(Wg + (nt*16 + (l&15))*FF + ks*32 + ((l>>4)<<3));
      acc[nt] = __builtin_amdgcn_mfma_f32_16x16x32_bf16(afr[ks], bfr, acc[nt], 0, 0, 0);
    }
  }
}

// ---------------- eqf: MLP(inv_msg) + mask*eqmsgF row-reduction ----------------
__global__ __launch_bounds__(256) void k_eqf_mfma(
    const unsigned short* __restrict__ Xbf,
    const unsigned short* __restrict__ W1bf, const float* __restrict__ b1,
    const unsigned short* __restrict__ W2bf, const float* __restrict__ b2,
    const float* __restrict__ eqmsgF, const float* __restrict__ maskp,
    float* __restrict__ eqf_out, float* __restrict__ updf){
  __shared__ unsigned short Xs[64*136];
  __shared__ unsigned short Hs[64*136];
  __shared__ float scal[64][4];
  __shared__ float afl[4][384];
  const int t = threadIdx.x, w = t>>6, l = t&63;
  const int atom = blockIdx.x;
  const unsigned short* xg = Xbf + (size_t)atom*NNB*FF;
  #pragma unroll
  for (int c = t; c < 1024; c += 256){
    int row = c >> 4, ko = (c & 15) << 3;
    *(int4*)(Xs + row*136 + ko) = *(const int4*)(xg + row*FF + ko);
  }
  if (t < 64){
    int eg = atom*NNB + t;
    scal[t][0] = eqmsgF[(size_t)eg*3+0];
    scal[t][1] = eqmsgF[(size_t)eg*3+1];
    scal[t][2] = eqmsgF[(size_t)eg*3+2];
    scal[t][3] = maskp[eg];
  }
  __syncthreads();
  f32x4 acc[8];
  #pragma unroll
  for (int nt=0;nt<8;++nt) acc[nt] = f32x4{0.f,0.f,0.f,0.f};
  gemm_tile(Xs, W1bf, w, l, acc);
  #pragma unroll
  for (int nt=0;nt<8;++nt){
    int col = nt*16 + (l&15);
    float bb = b1[col];
    #pragma unroll
    for (int r=0;r<4;++r){
      int row = w*16 + ((l>>4)<<2) + r;
      Hs[row*136 + col] = f2bf(silu_f(acc[nt][r] + bb));
    }
  }
  __syncthreads();
  #pragma unroll
  for (int nt=0;nt<8;++nt) acc[nt] = f32x4{0.f,0.f,0.f,0.f};
  gemm_tile(Hs, W2bf, w, l, acc);
  #pragma unroll
  for (int nt=0;nt<8;++nt){
    int col = nt*16 + (l&15);
    float bb = b2[col];
    float q0=0.f,q1=0.f,q2=0.f;
    #pragma unroll
    for (int r=0;r<4;++r){
      int row = w*16 + ((l>>4)<<2) + r;
      float ym = (acc[nt][r] + bb) * scal[row][3];
      q0 = fmaf(ym, scal[row][0], q0);
      q1 = fmaf(ym, scal[row][1], q1);
      q2 = fmaf(ym, scal[row][2], q2);
    }
    q0 += __shfl_xor(q0,16); q0 += __shfl_xor(q0,32);
    q1 += __shfl_xor(q1,16); q1 += __shfl_xor(q1,32);
    q2 += __shfl_xor(q2,16); q2 += __shfl_xor(q2,32);
    if (l < 16){
      afl[w][0*128+col] = q0;
      afl[w][1*128+col] = q1;
      afl[w][2*128+col] = q2;
    }
  }
  __syncthreads();
  for (int i=t; i<384; i+=256){
    float s = afl[0][i]+afl[1][i]+afl[2][i]+afl[3][i];
    size_t o = (size_t)atom*384 + i;
    updf[o] = s;
    eqf_out[o] += s;
  }
}

// ---------------- eme: MLP(inv_msg), gather eq_dr[neighbor], row-reduction ----------------
__global__ __launch_bounds__(256) void k_eme_mfma(
    const unsigned short* __restrict__ Xbf,
    const unsigned short* __restrict__ W1bf,
    const unsigned short* __restrict__ W2bf,
    const int* __restrict__ nbrs, const float* __restrict__ maskp,
    const float* __restrict__ eqdr, float* __restrict__ upddr){
  __shared__ unsigned short Xs[64*136];
  __shared__ unsigned short Hs[64*136];
  __shared__ float maskL[64];
  __shared__ int   nbq[64];
  __shared__ float afl[4][384];
  const int t = threadIdx.x, w = t>>6, l = t&63;
  const int atom = blockIdx.x;
  const unsigned short* xg = Xbf + (size_t)atom*NNB*FF;
  #pragma unroll
  for (int c = t; c < 1024; c += 256){
    int row = c >> 4, ko = (c & 15) << 3;
    *(int4*)(Xs + row*136 + ko) = *(const int4*)(xg + row*FF + ko);
  }
  if (t < 64){
    int eg = atom*NNB + t;
    maskL[t] = maskp[eg];
    nbq[t]   = (atom/AA)*AA + nbrs[eg];
  }
  __syncthreads();
  f32x4 acc[8];
  #pragma unroll
  for (int nt=0;nt<8;++nt) acc[nt] = f32x4{0.f,0.f,0.f,0.f};
  gemm_tile(Xs, W1bf, w, l, acc);
  #pragma unroll
  for (int nt=0;nt<8;++nt){
    int col = nt*16 + (l&15);
    #pragma unroll
    for (int r=0;r<4;++r){
      int row = w*16 + ((l>>4)<<2) + r;
      Hs[row*136 + col] = f2bf(silu_f(acc[nt][r]));
    }
  }
  __syncthreads();
  #pragma unroll
  for (int nt=0;nt<8;++nt) acc[nt] = f32x4{0.f,0.f,0.f,0.f};
  gemm_tile(Hs, W2bf, w, l, acc);
  #pragma unroll
  for (int nt=0;nt<8;++nt){
    int col = nt*16 + (l&15);
    float q0=0.f,q1=0.f,q2=0.f;
    #pragma unroll
    for (int r=0;r<4;++r){
      int row = w*16 + ((l>>4)<<2) + r;
      float ym = acc[nt][r] * maskL[row];
      const float* gd = eqdr + (size_t)nbq[row]*384 + col;
      q0 = fmaf(ym, gd[0],   q0);
      q1 = fmaf(ym, gd[128], q1);
      q2 = fmaf(ym, gd[256], q2);
    }
    q0 += __shfl_xor(q0,16); q0 += __shfl_xor(q0,32);
    q1 += __shfl_xor(q1,16); q1 += __shfl_xor(q1,32);
    q2 += __shfl_xor(q2,16); q2 += __shfl_xor(q2,32);
    if (l < 16){
      afl[w][0*128+col] = q0;
      afl[w][1*128+col] = q1;
      afl[w][2*128+col] = q2;
    }
  }
  __syncthreads();
  for (int i=t; i<384; i+=256){
    float s = afl[0][i]+afl[1][i]+afl[2][i]+afl[3][i];
    upddr[(size_t)atom*384 + i] = s;
  }
}

// ---------------- finalize: eq_dr update + inv_node update ----------------
__global__ void k_fin(const float* __restrict__ esu, const float* __restrict__ isu,
                      const float* __restrict__ updf, const float* __restrict__ upddr,
                      const float* __restrict__ eqf, float* __restrict__ eqdr,
                      float* __restrict__ inv_node){
  int id = blockIdx.x*256+threadIdx.x;
  int atom = id >> 7, o = id & 127;
  float es = esu[id];
  float sum = 0.f;
  size_t b0 = (size_t)atom*3*FF + o;
  #pragma unroll
  for (int c=0;c<3;++c){
    size_t k = b0 + (size_t)c*FF;
    float nd = eqdr[k] + upddr[k] + es*updf[k];
    eqdr[k] = nd;
    sum = fmaf(eqf[k], nd, sum);
  }
  inv_node[id] = fmaf(-isu[id], sum, inv_node[id]);
}

extern "C" void kernel_launch(void* const* d_in, const int* in_sizes, int n_in,
                              void* d_out, int out_size, void* d_ws, size_t ws_size,
                              hipStream_t stream){
  const int*   z     = (const int*)  d_in[0];
  const int*   nbrs  = (const int*)  d_in[2];
  const float* maskp = (const float*)d_in[3];
  const float* dist  = (const float*)d_in[4];
  const float* dvec  = (const float*)d_in[5];
  const float* emb   = (const float*)d_in[6];
  const float* me_W  = (const float*)d_in[7];
  const float* me_b  = (const float*)d_in[8];
  const float* mn_W1 = (const float*)d_in[9];
  const float* mn_b1 = (const float*)d_in[10];
  const float* mn_W2 = (const float*)d_in[11];
  const float* mn_b2 = (const float*)d_in[12];
  const float* eqc_W = (const float*)d_in[13];
  const float* eqf_W1= (const float*)d_in[14];
  const float* eqf_b1= (const float*)d_in[15];
  const float* eqf_W2= (const float*)d_in[16];
  const float* eqf_b2= (const float*)d_in[17];
  const float* esu_W1= (const float*)d_in[18];
  const float* esu_b1= (const float*)d_in[19];
  const float* esu_W2= (const float*)d_in[20];
  const float* esu_b2= (const float*)d_in[21];
  const float* eme_W1= (const float*)d_in[22];
  const float* eme_W2= (const float*)d_in[23];
  const float* isu_W1= (const float*)d_in[24];
  const float* isu_b1= (const float*)d_in[25];
  const float* isu_W2= (const float*)d_in[26];
  const float* isu_b2= (const float*)d_in[27];

  float* out      = (float*)d_out;
  float* inv_node = out;                        // BA*FF   = 131072
  float* eqF      = out + 131072;               // BA*3    = 3072
  float* eqf      = out + 134144;               // BA*3*FF = 393216
  float* eqdr     = out + 527360;               // BA*3*FF = 393216

  // workspace layout (floats)
  float* w        = (float*)d_ws;
  float* rbf      = w;                          // 1,310,720
  float* cutw     = w + 1310720;                //    65,536
  float* unitv    = w + 1376256;                //   196,608
  float* msg_node = w + 1572864;                //   131,072
  float* esu_o    = w + 1703936;                //   131,072
  float* isu_o    = w + 1835008;                //   131,072
  float* eqmsgF   = w + 1966080;                //   196,608
  float* updf     = w + 2162688;                //   393,216
  float* upddr    = w + 2555904;                //   393,216
  unsigned short* xbf = (unsigned short*)(w + 2949120);   // EDG*FF ushorts = 4,194,304 floats
  unsigned short* wbf = (unsigned short*)(w + 7143424);   // 196,608 ushorts

  hipMemsetAsync(out + 131072, 0, (size_t)(3072 + 2*393216)*sizeof(float), stream);

  k_cvtw<<<768, 256, 0, stream>>>(eqf_W1, eqf_W2, eme_W1, eme_W2, wbf);
  k_init<<<BA*FF/256, 256, 0, stream>>>(z, emb, inv_node);
  k_geom<<<EDG/256,   256, 0, stream>>>(dist, dvec, rbf, cutw, unitv);

  for (int l=0; l<NLAY; ++l){
    size_t oW = (size_t)l*FF*FF, oB = (size_t)l*FF, oM = (size_t)l*FF*FF;
    const unsigned short* eqfW1b = wbf + 0*49152 + l*16384;
    const unsigned short* eqfW2b = wbf + 1*49152 + l*16384;
    const unsigned short* emeW1b = wbf + 2*49152 + l*16384;
    const unsigned short* emeW2b = wbf + 3*49152 + l*16384;

    k_mlp_node3<<<dim3(BA/16, 3), 128, 0, stream>>>(inv_node,
        mn_W1+oW,  mn_b1+oB,  mn_W2+oW,  mn_b2+oB,  msg_node,
        esu_W1+oW, esu_b1+oB, esu_W2+oW, esu_b2+oB, esu_o,
        isu_W1+oW, isu_b1+oB, isu_W2+oW, isu_b2+oB, isu_o);
    k_edge_msg<<<BA, 256, 0, stream>>>(rbf, cutw, unitv, maskp, nbrs, msg_node,
                                       me_W + (size_t)l*FF*NBAS, me_b+oB, eqc_W+oB,
                                       xbf, eqmsgF, eqF);
    k_eqf_mfma<<<BA, 256, 0, stream>>>(xbf, eqfW1b, eqf_b1+oB, eqfW2b, eqf_b2+oB,
                                       eqmsgF, maskp, eqf, updf);
    k_eme_mfma<<<BA, 256, 0, stream>>>(xbf, emeW1b, emeW2b, nbrs, maskp, eqdr, upddr);
    k_fin<<<BA*FF/256, 256, 0, stream>>>(esu_o, isu_o, updf, upddr, eqf, eqdr, inv_node);
    (void)oM;
  }
}

// Round 3
// 341.680 us; speedup vs baseline: 7.0242x; 1.3123x over previous
//
#include <hip/hip_runtime.h>
#include <cstdint>
#include <cstddef>

#define BB   4
#define AA   256
#define NNB  64
#define FF   128
#define NBAS 20
#define NLAY 3
#define BA   (BB*AA)        // 1024 atoms total
#define EDG  (BA*NNB)       // 65536 edges

typedef __attribute__((ext_vector_type(8))) short bf16x8;
typedef __attribute__((ext_vector_type(4))) float f32x4;

__device__ __forceinline__ float silu_f(float x){ return x / (1.0f + __expf(-x)); }

// round-to-nearest-even f32 -> bf16 bits
__device__ __forceinline__ unsigned short f2bf(float x){
  unsigned int u = __float_as_uint(x);
  u += 0x7FFFu + ((u >> 16) & 1u);
  return (unsigned short)(u >> 16);
}
__device__ __forceinline__ unsigned int pk2(float a, float b){
  return (unsigned int)f2bf(a) | ((unsigned int)f2bf(b) << 16);
}

// ---------------- init: inv_node = emb[atomic_numbers] ----------------
__global__ void k_init(const int* __restrict__ z, const float* __restrict__ emb,
                       float* __restrict__ inv_node){
  int id = blockIdx.x*256 + threadIdx.x;
  int atom = id >> 7, o = id & 127;
  inv_node[id] = emb[z[atom]*FF + o];
}

// ---------------- geometry: bf16 rbf [EDG][32] (zero-padded), cutoff, unit ----------------
__global__ void k_geom(const float* __restrict__ dist, const float* __restrict__ dvec,
                       unsigned short* __restrict__ rbf_bf, float* __restrict__ cutw,
                       float* __restrict__ unitv){
  int e = blockIdx.x*256 + threadIdx.x;
  float d = dist[e];
  float x = d * 0.2f;
  float x2 = x*x, x4 = x2*x2, x6 = x4*x2, x7 = x6*x, x8 = x7*x;
  float f = 1.0f - 28.0f*x6 + 48.0f*x7 - 21.0f*x8;
  f = (x < 1.0f) ? f : 0.0f;
  cutw[e] = f;
  float inv = 1.0f/(d + 1e-8f);
  unitv[(size_t)e*3+0] = dvec[(size_t)e*3+0]*inv;
  unitv[(size_t)e*3+1] = dvec[(size_t)e*3+1]*inv;
  unitv[(size_t)e*3+2] = dvec[(size_t)e*3+2]*inv;
  const float c = 0.6283185307179586f;        // pi/5
  unsigned short* rb = rbf_bf + (size_t)e*32;
  #pragma unroll
  for (int n=1;n<=NBAS;++n) rb[n-1] = f2bf(sinf((float)n*c*d)*inv);
  #pragma unroll
  for (int k=NBAS;k<32;++k) rb[k] = 0;
}

// ------------- weight conversion: eqf_W1, eqf_W2, eme_W1, eme_W2 (+ padded me_W) ------------
__global__ void k_cvtw(const float* __restrict__ a, const float* __restrict__ b,
                       const float* __restrict__ c, const float* __restrict__ d,
                       const float* __restrict__ me, unsigned short* __restrict__ out){
  int id = blockIdx.x*256 + threadIdx.x;
  if (id < 196608){
    int reg = id / 49152, off = id - reg*49152;
    const float* src = (reg==0)?a:(reg==1)?b:(reg==2)?c:d;
    out[id] = f2bf(src[off]);
  } else if (id < 196608 + 12288){
    int p = id - 196608;
    int l = p >> 12;            // layer
    int rem = p & 4095;
    int row = rem >> 5, k = rem & 31;
    float v = (k < NBAS) ? me[((size_t)l*FF + row)*NBAS + k] : 0.0f;
    out[id] = f2bf(v);
  }
}

// ---------------- f32 two-pass MLP core over 16 rows (node MLPs) ----------------
__device__ __forceinline__ void mlp16(const float (*xs)[FF], float (*hs)[FF], int o,
    const float* __restrict__ W1, const float* __restrict__ b1,
    const float* __restrict__ W2, const float* __restrict__ b2, float acc[16]){
  #pragma unroll
  for (int r=0;r<16;++r) acc[r] = b1[o];
  #pragma unroll
  for (int ic=0;ic<4;++ic){
    float4 wv[8];
    #pragma unroll
    for (int j=0;j<8;++j) wv[j] = *reinterpret_cast<const float4*>(&W1[(size_t)o*FF + ic*32 + j*4]);
    #pragma unroll
    for (int r=0;r<16;++r){
      #pragma unroll
      for (int j=0;j<8;++j){
        float4 xv = *reinterpret_cast<const float4*>(&xs[r][ic*32+j*4]);
        acc[r] = fmaf(xv.x, wv[j].x, acc[r]);
        acc[r] = fmaf(xv.y, wv[j].y, acc[r]);
        acc[r] = fmaf(xv.z, wv[j].z, acc[r]);
        acc[r] = fmaf(xv.w, wv[j].w, acc[r]);
      }
    }
  }
  #pragma unroll
  for (int r=0;r<16;++r) hs[r][o] = silu_f(acc[r]);
  __syncthreads();
  #pragma unroll
  for (int r=0;r<16;++r) acc[r] = b2[o];
  #pragma unroll
  for (int ic=0;ic<4;++ic){
    float4 wv[8];
    #pragma unroll
    for (int j=0;j<8;++j) wv[j] = *reinterpret_cast<const float4*>(&W2[(size_t)o*FF + ic*32 + j*4]);
    #pragma unroll
    for (int r=0;r<16;++r){
      #pragma unroll
      for (int j=0;j<8;++j){
        float4 xv = *reinterpret_cast<const float4*>(&hs[r][ic*32+j*4]);
        acc[r] = fmaf(xv.x, wv[j].x, acc[r]);
        acc[r] = fmaf(xv.y, wv[j].y, acc[r]);
        acc[r] = fmaf(xv.z, wv[j].z, acc[r]);
        acc[r] = fmaf(xv.w, wv[j].w, acc[r]);
      }
    }
  }
}

// ---------------- three node MLPs in one dispatch (blockIdx.y selects) ----------------
__global__ __launch_bounds__(128) void k_mlp_node3(const float* __restrict__ X,
    const float* W1a, const float* b1a, const float* W2a, const float* b2a, float* Ya,
    const float* W1b, const float* b1b, const float* W2b, const float* b2b, float* Yb,
    const float* W1c, const float* b1c, const float* W2c, const float* b2c, float* Yc){
  const float *W1,*b1,*W2,*b2; float* Y;
  if (blockIdx.y==0){ W1=W1a;b1=b1a;W2=W2a;b2=b2a;Y=Ya; }
  else if (blockIdx.y==1){ W1=W1b;b1=b1b;W2=W2b;b2=b2b;Y=Yb; }
  else { W1=W1c;b1=b1c;W2=W2c;b2=b2c;Y=Yc; }
  __shared__ __align__(16) float xs[16][FF];
  __shared__ __align__(16) float hs[16][FF];
  const int o = threadIdx.x;
  const int row0 = blockIdx.x * 16;
  #pragma unroll
  for (int r=0;r<16;++r) xs[r][o] = X[(size_t)(row0+r)*FF + o];
  __syncthreads();
  float acc[16];
  mlp16(xs, hs, o, W1, b1, W2, b2, acc);
  #pragma unroll
  for (int r=0;r<16;++r) Y[(size_t)(row0+r)*FF + o] = acc[r];
}

// =====================================================================
// Fused per-layer edge kernel: one block = one atom (64 edges), 4 waves.
//   stage : me-MLP via MFMA (swapped) -> inv_msg (bf16, LDS), eqmsgF/eqF
//   eqf   : GEMM1 swapped -> H (packed LDS) -> GEMM2 -> masked reduce
//   eme   : GEMM1 swapped -> H             -> GEMM2 -> eqdr-gather reduce
// LDS tile Hs aliases X then H (X fragments held in registers).
// =====================================================================
__global__ __launch_bounds__(256) void k_edge_fused(
    const unsigned short* __restrict__ rbf_bf,
    const float* __restrict__ cutw, const float* __restrict__ unitv,
    const float* __restrict__ maskp, const int* __restrict__ nbrs,
    const float* __restrict__ msg_node,
    const unsigned short* __restrict__ meWb, const float* __restrict__ meb,
    const float* __restrict__ eqcW,
    const unsigned short* __restrict__ W1e, const float* __restrict__ b1e,
    const unsigned short* __restrict__ W2e, const float* __restrict__ b2e,
    const unsigned short* __restrict__ W1m, const unsigned short* __restrict__ W2m,
    const float* __restrict__ eqdr,
    float* __restrict__ eqF, float* __restrict__ eqf_out,
    float* __restrict__ updf, float* __restrict__ upddr){
  __shared__ unsigned short Hs[64*136];      // 17.4 KB, X then H (aliased)
  __shared__ float scal[64][4];              // eqmsgF xyz + mask
  __shared__ int   nbq[64];
  __shared__ float afl[4][384];
  __shared__ float eqFred[4][3];
  const int t = threadIdx.x, w = t>>6, l = t&63;
  const int atom = blockIdx.x;
  const int bbase = (atom/AA)*AA;
  const int le = w*16 + (l&15);              // lane's edge (stage + GEMM1 n-index)
  const int eg = atom*NNB + le;
  const int kg = (l>>4)<<3;                  // k-offset 0/8/16/24
  const int r0 = (l>>4)<<2;                  // row-offset 0/4/8/12 in D tiles

  if (t < 64){
    int e2 = atom*NNB + t;
    nbq[t]     = bbase + nbrs[e2];
    scal[t][3] = maskp[e2];
  }

  // ---------------- stage: me-MLP (K=32 padded) + inv_msg -> Hs ----------------
  f32x4 acc[8];
  {
    bf16x8 rfr = *(const bf16x8*)(rbf_bf + (size_t)eg*32 + kg);
    #pragma unroll
    for (int nt=0;nt<8;++nt){
      bf16x8 wfr = *(const bf16x8*)(meWb + (nt*16 + (l&15))*32 + kg);
      acc[nt] = __builtin_amdgcn_mfma_f32_16x16x32_bf16(wfr, rfr, f32x4{0.f,0.f,0.f,0.f}, 0,0,0);
    }
    const float ct = cutw[eg];
    const int   nbv = bbase + nbrs[eg];
    float pv = 0.f;
    #pragma unroll
    for (int nt=0;nt<8;++nt){
      int o0 = nt*16 + r0;
      float4 mb = *(const float4*)(meb + o0);
      float4 mi = *(const float4*)(msg_node + (size_t)atom*FF + o0);
      float4 mf = *(const float4*)(msg_node + (size_t)nbv*FF + o0);
      float4 ec = *(const float4*)(eqcW + o0);
      float v0 = (acc[nt][0]+mb.x)*ct*mi.x*mf.x;
      float v1 = (acc[nt][1]+mb.y)*ct*mi.y*mf.y;
      float v2 = (acc[nt][2]+mb.z)*ct*mi.z*mf.z;
      float v3 = (acc[nt][3]+mb.w)*ct*mi.w*mf.w;
      pv = fmaf(v0,ec.x, fmaf(v1,ec.y, fmaf(v2,ec.z, fmaf(v3,ec.w, pv))));
      uint2 u; u.x = pk2(v0,v1); u.y = pk2(v2,v3);
      *(uint2*)(&Hs[le*136 + o0]) = u;
    }
    pv += __shfl_xor(pv,16); pv += __shfl_xor(pv,32);
    float cf0=0.f, cf1=0.f, cf2=0.f;
    if (l < 16){
      float m  = scal[le][3];               // same value just written (t<64 path above)
      float s0 = pv*unitv[(size_t)eg*3+0];
      float s1 = pv*unitv[(size_t)eg*3+1];
      float s2 = pv*unitv[(size_t)eg*3+2];
      scal[le][0]=s0; scal[le][1]=s1; scal[le][2]=s2;
      cf0 = s0*m; cf1 = s1*m; cf2 = s2*m;
    }
    #pragma unroll
    for (int s2=1; s2<16; s2<<=1){
      cf0 += __shfl_xor(cf0,s2); cf1 += __shfl_xor(cf1,s2); cf2 += __shfl_xor(cf2,s2);
    }
    if (l == 0){ eqFred[w][0]=cf0; eqFred[w][1]=cf1; eqFred[w][2]=cf2; }
  }
  __syncthreads();

  // X fragments -> registers (reused by both GEMM1s)
  bf16x8 xfrag[4];
  #pragma unroll
  for (int ks=0;ks<4;++ks)
    xfrag[ks] = *(const bf16x8*)(Hs + le*136 + ks*32 + kg);
  __syncthreads();                           // Xs reads done before H overwrite

  // ---------------- eqf GEMM1 (swapped) -> Hs ----------------
  #pragma unroll
  for (int nt=0;nt<8;++nt) acc[nt] = f32x4{0.f,0.f,0.f,0.f};
  #pragma unroll
  for (int nt=0;nt<8;++nt)
    #pragma unroll
    for (int ks=0;ks<4;++ks){
      bf16x8 wfr = *(const bf16x8*)(W1e + (nt*16+(l&15))*FF + ks*32 + kg);
      acc[nt] = __builtin_amdgcn_mfma_f32_16x16x32_bf16(wfr, xfrag[ks], acc[nt], 0,0,0);
    }
  #pragma unroll
  for (int nt=0;nt<8;++nt){
    int o0 = nt*16 + r0;
    float4 bb = *(const float4*)(b1e + o0);
    uint2 u;
    u.x = pk2(silu_f(acc[nt][0]+bb.x), silu_f(acc[nt][1]+bb.y));
    u.y = pk2(silu_f(acc[nt][2]+bb.z), silu_f(acc[nt][3]+bb.w));
    *(uint2*)(&Hs[le*136 + o0]) = u;
  }
  __syncthreads();

  // ---------------- eqf GEMM2 (unswapped) + masked scal reduce ----------------
  {
    bf16x8 hfr[4];
    #pragma unroll
    for (int ks=0;ks<4;++ks)
      hfr[ks] = *(const bf16x8*)(Hs + le*136 + ks*32 + kg);
    #pragma unroll
    for (int nt=0;nt<8;++nt) acc[nt] = f32x4{0.f,0.f,0.f,0.f};
    #pragma unroll
    for (int nt=0;nt<8;++nt)
      #pragma unroll
      for (int ks=0;ks<4;++ks){
        bf16x8 wfr = *(const bf16x8*)(W2e + (nt*16+(l&15))*FF + ks*32 + kg);
        acc[nt] = __builtin_amdgcn_mfma_f32_16x16x32_bf16(hfr[ks], wfr, acc[nt], 0,0,0);
      }
    #pragma unroll
    for (int nt=0;nt<8;++nt){
      int col = nt*16 + (l&15);
      float bb = b2e[col];
      float q0=0.f,q1=0.f,q2=0.f;
      #pragma unroll
      for (int r=0;r<4;++r){
        int row = w*16 + r0 + r;
        float ym = (acc[nt][r] + bb) * scal[row][3];
        q0 = fmaf(ym, scal[row][0], q0);
        q1 = fmaf(ym, scal[row][1], q1);
        q2 = fmaf(ym, scal[row][2], q2);
      }
      q0 += __shfl_xor(q0,16); q0 += __shfl_xor(q0,32);
      q1 += __shfl_xor(q1,16); q1 += __shfl_xor(q1,32);
      q2 += __shfl_xor(q2,16); q2 += __shfl_xor(q2,32);
      if (l < 16){
        afl[w][0*128+col] = q0; afl[w][1*128+col] = q1; afl[w][2*128+col] = q2;
      }
    }
  }
  __syncthreads();
  for (int i=t; i<384; i+=256){
    float s = afl[0][i]+afl[1][i]+afl[2][i]+afl[3][i];
    size_t o = (size_t)atom*384 + i;
    updf[o] = s;
    eqf_out[o] += s;
  }
  if (t < 3) eqF[atom*3+t] += eqFred[0][t]+eqFred[1][t]+eqFred[2][t]+eqFred[3][t];
  __syncthreads();

  // ---------------- eme GEMM1 (swapped, no bias) -> Hs ----------------
  #pragma unroll
  for (int nt=0;nt<8;++nt) acc[nt] = f32x4{0.f,0.f,0.f,0.f};
  #pragma unroll
  for (int nt=0;nt<8;++nt)
    #pragma unroll
    for (int ks=0;ks<4;++ks){
      bf16x8 wfr = *(const bf16x8*)(W1m + (nt*16+(l&15))*FF + ks*32 + kg);
      acc[nt] = __builtin_amdgcn_mfma_f32_16x16x32_bf16(wfr, xfrag[ks], acc[nt], 0,0,0);
    }
  #pragma unroll
  for (int nt=0;nt<8;++nt){
    int o0 = nt*16 + r0;
    uint2 u;
    u.x = pk2(silu_f(acc[nt][0]), silu_f(acc[nt][1]));
    u.y = pk2(silu_f(acc[nt][2]), silu_f(acc[nt][3]));
    *(uint2*)(&Hs[le*136 + o0]) = u;
  }
  __syncthreads();

  // ---------------- eme GEMM2 (unswapped) + eqdr-gather reduce ----------------
  {
    bf16x8 hfr[4];
    #pragma unroll
    for (int ks=0;ks<4;++ks)
      hfr[ks] = *(const bf16x8*)(Hs + le*136 + ks*32 + kg);
    #pragma unroll
    for (int nt=0;nt<8;++nt) acc[nt] = f32x4{0.f,0.f,0.f,0.f};
    #pragma unroll
    for (int nt=0;nt<8;++nt)
      #pragma unroll
      for (int ks=0;ks<4;++ks){
        bf16x8 wfr = *(const bf16x8*)(W2m + (nt*16+(l&15))*FF + ks*32 + kg);
        acc[nt] = __builtin_amdgcn_mfma_f32_16x16x32_bf16(hfr[ks], wfr, acc[nt], 0,0,0);
      }
    #pragma unroll
    for (int nt=0;nt<8;++nt){
      int col = nt*16 + (l&15);
      float q0=0.f,q1=0.f,q2=0.f;
      #pragma unroll
      for (int r=0;r<4;++r){
        int row = w*16 + r0 + r;
        float ym = acc[nt][r] * scal[row][3];
        const float* gd = eqdr + (size_t)nbq[row]*384 + col;
        q0 = fmaf(ym, gd[0],   q0);
        q1 = fmaf(ym, gd[128], q1);
        q2 = fmaf(ym, gd[256], q2);
      }
      q0 += __shfl_xor(q0,16); q0 += __shfl_xor(q0,32);
      q1 += __shfl_xor(q1,16); q1 += __shfl_xor(q1,32);
      q2 += __shfl_xor(q2,16); q2 += __shfl_xor(q2,32);
      if (l < 16){
        afl[w][0*128+col] = q0; afl[w][1*128+col] = q1; afl[w][2*128+col] = q2;
      }
    }
  }
  __syncthreads();
  for (int i=t; i<384; i+=256){
    upddr[(size_t)atom*384 + i] = afl[0][i]+afl[1][i]+afl[2][i]+afl[3][i];
  }
}

// ---------------- finalize: eq_dr update + inv_node update ----------------
__global__ void k_fin(const float* __restrict__ esu, const float* __restrict__ isu,
                      const float* __restrict__ updf, const float* __restrict__ upddr,
                      const float* __restrict__ eqf, float* __restrict__ eqdr,
                      float* __restrict__ inv_node){
  int id = blockIdx.x*256+threadIdx.x;
  int atom = id >> 7, o = id & 127;
  float es = esu[id];
  float sum = 0.f;
  size_t b0 = (size_t)atom*3*FF + o;
  #pragma unroll
  for (int c=0;c<3;++c){
    size_t k = b0 + (size_t)c*FF;
    float nd = eqdr[k] + upddr[k] + es*updf[k];
    eqdr[k] = nd;
    sum = fmaf(eqf[k], nd, sum);
  }
  inv_node[id] = fmaf(-isu[id], sum, inv_node[id]);
}

extern "C" void kernel_launch(void* const* d_in, const int* in_sizes, int n_in,
                              void* d_out, int out_size, void* d_ws, size_t ws_size,
                              hipStream_t stream){
  const int*   z     = (const int*)  d_in[0];
  const int*   nbrs  = (const int*)  d_in[2];
  const float* maskp = (const float*)d_in[3];
  const float* dist  = (const float*)d_in[4];
  const float* dvec  = (const float*)d_in[5];
  const float* emb   = (const float*)d_in[6];
  const float* me_W  = (const float*)d_in[7];
  const float* me_b  = (const float*)d_in[8];
  const float* mn_W1 = (const float*)d_in[9];
  const float* mn_b1 = (const float*)d_in[10];
  const float* mn_W2 = (const float*)d_in[11];
  const float* mn_b2 = (const float*)d_in[12];
  const float* eqc_W = (const float*)d_in[13];
  const float* eqf_W1= (const float*)d_in[14];
  const float* eqf_b1= (const float*)d_in[15];
  const float* eqf_W2= (const float*)d_in[16];
  const float* eqf_b2= (const float*)d_in[17];
  const float* esu_W1= (const float*)d_in[18];
  const float* esu_b1= (const float*)d_in[19];
  const float* esu_W2= (const float*)d_in[20];
  const float* esu_b2= (const float*)d_in[21];
  const float* eme_W1= (const float*)d_in[22];
  const float* eme_W2= (const float*)d_in[23];
  const float* isu_W1= (const float*)d_in[24];
  const float* isu_b1= (const float*)d_in[25];
  const float* isu_W2= (const float*)d_in[26];
  const float* isu_b2= (const float*)d_in[27];

  float* out      = (float*)d_out;
  float* inv_node = out;                        // BA*FF   = 131072
  float* eqF      = out + 131072;               // BA*3    = 3072
  float* eqf      = out + 134144;               // BA*3*FF = 393216
  float* eqdr     = out + 527360;               // BA*3*FF = 393216

  // workspace layout (floats)
  float* w        = (float*)d_ws;
  float* cutw     = w;                          //    65,536
  float* unitv    = w + 65536;                  //   196,608
  float* msg_node = w + 262144;                 //   131,072
  float* esu_o    = w + 393216;                 //   131,072
  float* isu_o    = w + 524288;                 //   131,072
  float* updf     = w + 655360;                 //   393,216
  float* upddr    = w + 1048576;                //   393,216
  unsigned short* rbf_bf = (unsigned short*)(w + 1441792); // EDG*32 us = 1,048,576 f
  unsigned short* wbf    = (unsigned short*)(w + 2490368); // 208,896 us

  hipMemsetAsync(out + 131072, 0, (size_t)(3072 + 2*393216)*sizeof(float), stream);

  k_cvtw<<<817, 256, 0, stream>>>(eqf_W1, eqf_W2, eme_W1, eme_W2, me_W, wbf);
  k_init<<<BA*FF/256, 256, 0, stream>>>(z, emb, inv_node);
  k_geom<<<EDG/256,   256, 0, stream>>>(dist, dvec, rbf_bf, cutw, unitv);

  for (int l=0; l<NLAY; ++l){
    size_t oW = (size_t)l*FF*FF, oB = (size_t)l*FF;
    const unsigned short* eqfW1b = wbf + 0*49152 + l*16384;
    const unsigned short* eqfW2b = wbf + 1*49152 + l*16384;
    const unsigned short* emeW1b = wbf + 2*49152 + l*16384;
    const unsigned short* emeW2b = wbf + 3*49152 + l*16384;
    const unsigned short* meWb   = wbf + 196608  + l*4096;

    k_mlp_node3<<<dim3(BA/16, 3), 128, 0, stream>>>(inv_node,
        mn_W1+oW,  mn_b1+oB,  mn_W2+oW,  mn_b2+oB,  msg_node,
        esu_W1+oW, esu_b1+oB, esu_W2+oW, esu_b2+oB, esu_o,
        isu_W1+oW, isu_b1+oB, isu_W2+oW, isu_b2+oB, isu_o);
    k_edge_fused<<<BA, 256, 0, stream>>>(rbf_bf, cutw, unitv, maskp, nbrs, msg_node,
        meWb, me_b+oB, eqc_W+oB,
        eqfW1b, eqf_b1+oB, eqfW2b, eqf_b2+oB,
        emeW1b, emeW2b,
        eqdr, eqF, eqf, updf, upddr);
    k_fin<<<BA*FF/256, 256, 0, stream>>>(esu_o, isu_o, updf, upddr, eqf, eqdr, inv_node);
  }
}